// Round 6
// baseline (982.968 us; speedup 1.0000x reference)
//
#include <hip/hip_runtime.h>
#include <cstdint>

#define NVEH  4096
#define NT    1024
#define INW   12
#define UNITS 20

typedef float f32x2 __attribute__((ext_vector_type(2)));

#define PIN(v)  asm volatile("" : "+v"(v))

// Weight-broadcast packed FMA. Weights are stored as k-adjacent pairs
// {w_2k, w_2k+1}; op_sel broadcasts ONE half of src0 to both result halves,
// while src1 (the {vehA, vehB} data pair) stays elementwise.
// acc.{lo,hi} += w.LO * d.{lo,hi}
#define PKW_LO(acc, w, d) \
    asm("v_pk_fma_f32 %0, %1, %2, %0 op_sel:[0,0,0] op_sel_hi:[0,1,1]" \
        : "+v"(acc) : "v"(w), "v"(d))
// acc.{lo,hi} += w.HI * d.{lo,hi}
#define PKW_HI(acc, w, d) \
    asm("v_pk_fma_f32 %0, %1, %2, %0 op_sel:[1,0,0] op_sel_hi:[1,1,1]" \
        : "+v"(acc) : "v"(w), "v"(d))
// dst.{lo,hi} = w.LO * d.{lo,hi}   (chain-head init)
#define PKWMUL_LO(dst, w, d) \
    asm("v_pk_mul_f32 %0, %1, %2 op_sel:[0,0] op_sel_hi:[0,1]" \
        : "=v"(dst) : "v"(w), "v"(d))

__device__ __forceinline__ float fexp2(float x) { return __builtin_amdgcn_exp2f(x); }
__device__ __forceinline__ float frcp(float x)  { return __builtin_amdgcn_rcpf(x); }

// async global -> LDS, 16B per active lane, dest = uniform base + lane*16
__device__ __forceinline__ void gload_lds16(const float* g, float* l) {
    __builtin_amdgcn_global_load_lds(
        (const __attribute__((address_space(1))) unsigned int*)g,
        (__attribute__((address_space(3))) unsigned int*)l,
        16, 0, 0);
}

// 6 vehicles per wave (3 groups x vehicle-PAIR packed in f32x2 halves).
// 683 waves on 1024 SIMDs -> every SIMD holds at most ONE wave: the fixed
// per-step serial latency (LDS h-round-trip + transcendental chain) is paid
// once per 6 vehicles instead of per 3 with 2-wave contention on top.
__global__ __attribute__((amdgpu_waves_per_eu(1, 1))) __launch_bounds__(64)
void rnncf_kernel(const float* __restrict__ x,          // (NVEH, NT, 12)
                  const float* __restrict__ init_state, // (NVEH, 2)
                  const float* __restrict__ hs,         // (2, NVEH, 20)
                  const float* __restrict__ K,          // (12, 80)
                  const float* __restrict__ R,          // (20, 80)
                  const float* __restrict__ bias,       // (80)
                  const float* __restrict__ W2,         // (20, 10)
                  const float* __restrict__ b2,         // (10)
                  const float* __restrict__ Wlc,        // (10, 3)
                  const float* __restrict__ blc,        // (3)
                  const float* __restrict__ W1,         // (10, 1)
                  const float* __restrict__ b1,         // (1)
                  float* __restrict__ out)
{
    const int lane = threadIdx.x;
    const int grp  = lane / 20;          // 0..2 = vehicle-pair slot, 3 = idle
    const int sub  = lane % 20;          // unit index
    const int gc   = (grp < 3) ? grp : 2;   // clamped for idle-lane reads
    const int vA   = blockIdx.x * 6 + gc * 2;
    const int vB   = vA + 1;
    const bool aA  = (grp < 3) && (vA < NVEH);
    const bool aB  = (grp < 3) && (vB < NVEH);
    const int vsA  = (vA < NVEH) ? vA : NVEH - 1;
    const int vsB  = (vB < NVEH) ? vB : NVEH - 1;

    __shared__ __align__(16) float x_lds[8][6][12];   // depth-8 x FIFO
    __shared__ __align__(16) f32x2 h_lds[3][20];      // {hA, hB} per unit
    __shared__ __align__(16) f32x2 x2_lds[3][10];     // {x2A, x2B} per head

    // ---- per-lane weights, PRE-SCALED by the gate's exp2 constant.
    // Stored as k-adjacent pairs {w_2k, w_2k+1}: 1 register per weight,
    // consumed by PKW_LO/PKW_HI broadcast.
    const float L2E = 1.4426950408889634f;
    f32x2 Kp[4][6], Rp[4][10], bz2[4];
#pragma unroll
    for (int g = 0; g < 4; ++g) {
        const float s = (g == 2) ? (2.0f * L2E) : (-L2E);   // i,f,o: -L2E; g: +2*L2E
        bz2[g][0] = bz2[g][1] = s * bias[g * 20 + sub];
#pragma unroll
        for (int kp = 0; kp < 6; ++kp) {
            Kp[g][kp][0] = s * K[(2 * kp)     * 80 + g * 20 + sub];
            Kp[g][kp][1] = s * K[(2 * kp + 1) * 80 + g * 20 + sub];
        }
#pragma unroll
        for (int kp = 0; kp < 10; ++kp) {
            Rp[g][kp][0] = s * R[(2 * kp)     * 80 + g * 20 + sub];
            Rp[g][kp][1] = s * R[(2 * kp + 1) * 80 + g * 20 + sub];
        }
    }
    const int mh = (sub < 10) ? sub : 9;
    f32x2 W2p[10];                       // u-adjacent pairs of W2 column mh
#pragma unroll
    for (int up = 0; up < 10; ++up) {
        W2p[up][0] = W2[(2 * up)     * 10 + mh];
        W2p[up][1] = W2[(2 * up + 1) * 10 + mh];
    }
    f32x2 b2s2; b2s2[0] = b2s2[1] = b2[mh];
    const int jl = (sub < 3) ? sub : 0;
    f32x2 Wlcp[5];                       // m-adjacent pairs of Wlc column jl
#pragma unroll
    for (int mp = 0; mp < 5; ++mp) {
        Wlcp[mp][0] = Wlc[(2 * mp)     * 3 + jl];
        Wlcp[mp][1] = Wlc[(2 * mp + 1) * 3 + jl];
    }
    float blcs = blc[jl];
#pragma unroll
    for (int g = 0; g < 4; ++g) {
        PIN(bz2[g]);
#pragma unroll
        for (int kp = 0; kp < 6; ++kp)  PIN(Kp[g][kp]);
#pragma unroll
        for (int kp = 0; kp < 10; ++kp) PIN(Rp[g][kp]);
    }
#pragma unroll
    for (int up = 0; up < 10; ++up) PIN(W2p[up]);
#pragma unroll
    for (int mp = 0; mp < 5; ++mp)  PIN(Wlcp[mp]);
    PIN(b2s2); PIN(blcs);

    // ---- packed per-vehicle-pair state ----
    f32x2 pos2, spd2, c2, hnew2;
    pos2[0] = init_state[vsA * 2 + 0]; pos2[1] = init_state[vsB * 2 + 0];
    spd2[0] = init_state[vsA * 2 + 1]; spd2[1] = init_state[vsB * 2 + 1];
    c2[0]   = hs[(size_t)NVEH * UNITS + (size_t)vsA * UNITS + sub];
    c2[1]   = hs[(size_t)NVEH * UNITS + (size_t)vsB * UNITS + sub];
    hnew2[0] = hs[(size_t)vsA * UNITS + sub];
    hnew2[1] = hs[(size_t)vsB * UNITS + sub];

    if (grp < 3) h_lds[grp][sub] = hnew2;
    __builtin_amdgcn_wave_barrier();
    f32x2 hrp2[20];
#pragma unroll
    for (int q = 0; q < 10; ++q) {
        float4 v = ((const float4*)&h_lds[gc][0])[q];
        hrp2[2*q][0]   = v.x; hrp2[2*q][1]   = v.y;
        hrp2[2*q+1][0] = v.z; hrp2[2*q+1][1] = v.w;
    }
    __builtin_amdgcn_wave_barrier();

    // ---- deep x FIFO: lanes 0..17 stage 16B/step directly into LDS ----
    // lane L -> local vehicle L/3, quarter L%3; dest base + L*16 lands at
    // x_lds[slot][L/3][(L%3)*4].
    const bool stg = (lane < 18);
    int sveh = blockIdx.x * 6 + lane / 3;
    if (sveh > NVEH - 1) sveh = NVEH - 1;
    const float* sgp = x + (size_t)sveh * NT * INW + (lane % 3) * 4;

    if (stg) {
#pragma unroll
        for (int t0 = 0; t0 < 8; ++t0)
            gload_lds16(sgp + (size_t)t0 * INW, &x_lds[t0][0][0]);
    }

    float* trajpA = out + (size_t)vsA * NT;
    float* trajpB = out + (size_t)vsB * NT;
    float* lcpA   = out + (size_t)NVEH * NT + (size_t)vsA * NT * 3;
    float* lcpB   = out + (size_t)NVEH * NT + (size_t)vsB * NT * 3;

    for (int tb = 0; tb < NT; tb += 4) {
        // loads for steps tb..tb+3 were issued 2 blocks ago; newest 4 stay
        // in flight. Never drains to 0.
        asm volatile("s_waitcnt vmcnt(4)" ::: "memory");

#pragma unroll
        for (int j = 0; j < 4; ++j) {
            const int t = tb + j;

            // 1. read raw x_t for both vehicles + deferred-head x2 pairs
            const float4* xba = (const float4*)&x_lds[t & 7][gc * 2][0];
            const float4* xbb = (const float4*)&x_lds[t & 7][gc * 2 + 1][0];
            float4 uA0 = xba[0], uA1 = xba[1], uA2 = xba[2];
            float4 uB0 = xbb[0], uB1 = xbb[1], uB2 = xbb[2];
            f32x2 x2p[10];
            if (t > 0) {
#pragma unroll
                for (int q = 0; q < 5; ++q) {
                    float4 v = ((const float4*)&x2_lds[gc][0])[q];
                    x2p[2*q][0]   = v.x; x2p[2*q][1]   = v.y;
                    x2p[2*q+1][0] = v.z; x2p[2*q+1][1] = v.w;
                }
            }
            __builtin_amdgcn_wave_barrier();

            // 2. transform raw x -> packed inp pairs {A,B} (inputs NaN-free)
            const float ppA = pos2[0] * 0.01f, ppB = pos2[1] * 0.01f;
            f32x2 inp2[12];
            inp2[0][0]  = fmaf(uA0.x,  0.01f, -ppA); inp2[0][1]  = fmaf(uB0.x,  0.01f, -ppB);
            inp2[1][0]  = fmaf(uA0.y,  0.01f, -ppA); inp2[1][1]  = fmaf(uB0.y,  0.01f, -ppB);
            inp2[2][0]  = fmaf(uA0.z,  0.01f, -ppA); inp2[2][1]  = fmaf(uB0.z,  0.01f, -ppB);
            inp2[3][0]  = fmaf(uA0.w, -0.01f,  ppA); inp2[3][1]  = fmaf(uB0.w, -0.01f,  ppB);
            inp2[4][0]  = fmaf(uA1.x, -0.01f,  ppA); inp2[4][1]  = fmaf(uB1.x, -0.01f,  ppB);
            inp2[5][0]  = fmaf(uA1.y, -0.01f,  ppA); inp2[5][1]  = fmaf(uB1.y, -0.01f,  ppB);
            inp2[6][0]  = uA1.z * 0.025f;            inp2[6][1]  = uB1.z * 0.025f;
            inp2[7][0]  = uA1.w * 0.025f;            inp2[7][1]  = uB1.w * 0.025f;
            inp2[8][0]  = uA2.x * 0.025f;            inp2[8][1]  = uB2.x * 0.025f;
            inp2[9][0]  = uA2.y * 0.025f;            inp2[9][1]  = uB2.y * 0.025f;
            inp2[10][0] = uA2.z * 0.025f;            inp2[10][1] = uB2.z * 0.025f;
            inp2[11][0] = uA2.w * 0.025f;            inp2[11][1] = uB2.w * 0.025f;

            // 3. gate pre-activations, 4 packed accs {A,B}. Association
            //    matches r3's verified (zK + zA) + zB order.
            f32x2 zK[4], zA[4], zB[4];
#pragma unroll
            for (int g = 0; g < 4; ++g) {
                zK[g] = bz2[g];
#pragma unroll
                for (int kp = 0; kp < 6; ++kp) {
                    PKW_LO(zK[g], Kp[g][kp], inp2[2*kp]);
                    PKW_HI(zK[g], Kp[g][kp], inp2[2*kp+1]);
                }
            }
#pragma unroll
            for (int g = 0; g < 4; ++g) {
                PKWMUL_LO(zA[g], Rp[g][0], hrp2[0]);
                PKW_HI   (zA[g], Rp[g][0], hrp2[1]);
#pragma unroll
                for (int kp = 1; kp < 5; ++kp) {
                    PKW_LO(zA[g], Rp[g][kp], hrp2[2*kp]);
                    PKW_HI(zA[g], Rp[g][kp], hrp2[2*kp+1]);
                }
                PKWMUL_LO(zB[g], Rp[g][5], hrp2[10]);
                PKW_HI   (zB[g], Rp[g][5], hrp2[11]);
#pragma unroll
                for (int kp = 6; kp < 10; ++kp) {
                    PKW_LO(zB[g], Rp[g][kp], hrp2[2*kp]);
                    PKW_HI(zB[g], Rp[g][kp], hrp2[2*kp+1]);
                }
            }
            f32x2 z0 = (zK[0] + zA[0]) + zB[0];
            f32x2 z1 = (zK[1] + zA[1]) + zB[1];
            f32x2 z2 = (zK[2] + zA[2]) + zB[2];
            f32x2 z3 = (zK[3] + zA[3]) + zB[3];

            // 4. deferred head finish: acc(t-1) -> spd_t (W1/b1 via SGPRs)
            if (t > 0) {
                float a0 = b1[0], a1 = b1[0];
#pragma unroll
                for (int m = 0; m < 10; ++m) {
                    a0 = fmaf(x2p[m][0], W1[m], a0);
                    a1 = fmaf(x2p[m][1], W1[m], a1);
                }
                spd2[0] = fmaf(0.1f, fmaf(10.0f, a0, -6.0f), spd2[0]);
                spd2[1] = fmaf(0.1f, fmaf(10.0f, a1, -6.0f), spd2[1]);
                if (grp < 3 && sub < 3) {
                    f32x2 lc2; lc2[0] = blcs; lc2[1] = blcs;
#pragma unroll
                    for (int mp = 0; mp < 5; ++mp) {
                        PKW_LO(lc2, Wlcp[mp], x2p[2*mp]);
                        PKW_HI(lc2, Wlcp[mp], x2p[2*mp+1]);
                    }
                    if (aA) lcpA[(t - 1) * 3 + sub] = lc2[0];
                    if (aB) lcpB[(t - 1) * 3 + sub] = lc2[1];
                }
            }

            // 5. cell update, both vehicles (weights pre-scaled)
            f32x2 ig2, fg2, gg2, og2;
            ig2[0] = frcp(1.0f + fexp2(z0[0])); ig2[1] = frcp(1.0f + fexp2(z0[1]));
            fg2[0] = frcp(1.0f + fexp2(z1[0])); fg2[1] = frcp(1.0f + fexp2(z1[1]));
            gg2[0] = 1.0f - 2.0f * frcp(fexp2(z2[0]) + 1.0f);
            gg2[1] = 1.0f - 2.0f * frcp(fexp2(z2[1]) + 1.0f);
            og2[0] = frcp(1.0f + fexp2(z3[0])); og2[1] = frcp(1.0f + fexp2(z3[1]));
            c2 = fg2 * c2 + ig2 * gg2;
            f32x2 th2;
            th2[0] = 1.0f - 2.0f * frcp(fexp2(2.8853900817779268f * c2[0]) + 1.0f);
            th2[1] = 1.0f - 2.0f * frcp(fexp2(2.8853900817779268f * c2[1]) + 1.0f);
            hnew2 = og2 * th2;

            // 6. pos update + traj output (uses spd_t)
            f32x2 posn2 = pos2;
            posn2[0] = fmaf(0.1f, spd2[0], pos2[0]);
            posn2[1] = fmaf(0.1f, spd2[1], pos2[1]);
            if (sub == 0) {
                if (aA) trajpA[t] = posn2[0];
                if (aB) trajpB[t] = posn2[1];
            }
            pos2 = posn2;

            // 7. share packed h_new, reload into pairs
            if (grp < 3) h_lds[grp][sub] = hnew2;
            __builtin_amdgcn_wave_barrier();
#pragma unroll
            for (int q = 0; q < 10; ++q) {
                float4 v = ((const float4*)&h_lds[gc][0])[q];
                hrp2[2*q][0]   = v.x; hrp2[2*q][1]   = v.y;
                hrp2[2*q+1][0] = v.z; hrp2[2*q+1][1] = v.w;
            }
            __builtin_amdgcn_wave_barrier();

            // 8. head part 1: xm = relu(h . W2[:,mh] + b2[mh]), both vehicles
            f32x2 xm2 = b2s2;
#pragma unroll
            for (int up = 0; up < 10; ++up) {
                PKW_LO(xm2, W2p[up], hrp2[2*up]);
                PKW_HI(xm2, W2p[up], hrp2[2*up+1]);
            }
            xm2[0] = fmaxf(xm2[0], 0.0f);
            xm2[1] = fmaxf(xm2[1], 0.0f);
            if (grp < 3 && sub < 10) x2_lds[grp][sub] = xm2;
            __builtin_amdgcn_wave_barrier();
        }

        // issue loads for steps tb+8 .. tb+11 into the slots just consumed
        if (stg) {
#pragma unroll
            for (int j = 0; j < 4; ++j) {
                int tt = tb + 8 + j; if (tt > NT - 1) tt = NT - 1;
                gload_lds16(sgp + (size_t)tt * INW, &x_lds[(tb + j) & 7][0][0]);
            }
        }
    }

    // ---- epilogue: finish head for step NT-1 ----
    {
        f32x2 x2p[10];
#pragma unroll
        for (int q = 0; q < 5; ++q) {
            float4 v = ((const float4*)&x2_lds[gc][0])[q];
            x2p[2*q][0]   = v.x; x2p[2*q][1]   = v.y;
            x2p[2*q+1][0] = v.z; x2p[2*q+1][1] = v.w;
        }
        float a0 = b1[0], a1 = b1[0];
#pragma unroll
        for (int m = 0; m < 10; ++m) {
            a0 = fmaf(x2p[m][0], W1[m], a0);
            a1 = fmaf(x2p[m][1], W1[m], a1);
        }
        spd2[0] = fmaf(0.1f, fmaf(10.0f, a0, -6.0f), spd2[0]);
        spd2[1] = fmaf(0.1f, fmaf(10.0f, a1, -6.0f), spd2[1]);
        if (grp < 3 && sub < 3) {
            f32x2 lc2; lc2[0] = blcs; lc2[1] = blcs;
#pragma unroll
            for (int mp = 0; mp < 5; ++mp) {
                PKW_LO(lc2, Wlcp[mp], x2p[2*mp]);
                PKW_HI(lc2, Wlcp[mp], x2p[2*mp+1]);
            }
            if (aA) lcpA[(NT - 1) * 3 + sub] = lc2[0];
            if (aB) lcpB[(NT - 1) * 3 + sub] = lc2[1];
        }
    }

    {
        float* spdf = out + (size_t)NVEH * NT * 4;
        float* hf   = spdf + NVEH;
        float* cf   = hf + (size_t)NVEH * UNITS;
        if (sub == 0) {
            if (aA) spdf[vA] = spd2[0];
            if (aB) spdf[vB] = spd2[1];
        }
        if (aA) {
            hf[(size_t)vA * UNITS + sub] = hnew2[0];
            cf[(size_t)vA * UNITS + sub] = c2[0];
        }
        if (aB) {
            hf[(size_t)vB * UNITS + sub] = hnew2[1];
            cf[(size_t)vB * UNITS + sub] = c2[1];
        }
    }
}

extern "C" void kernel_launch(void* const* d_in, const int* in_sizes, int n_in,
                              void* d_out, int out_size, void* d_ws, size_t ws_size,
                              hipStream_t stream) {
    const float* x    = (const float*)d_in[0];
    const float* st0  = (const float*)d_in[1];
    const float* hs   = (const float*)d_in[2];
    const float* K    = (const float*)d_in[3];
    const float* R    = (const float*)d_in[4];
    const float* bias = (const float*)d_in[5];
    const float* W2   = (const float*)d_in[6];
    const float* b2   = (const float*)d_in[7];
    const float* Wlc  = (const float*)d_in[8];
    const float* blc  = (const float*)d_in[9];
    const float* W1   = (const float*)d_in[10];
    const float* b1   = (const float*)d_in[11];
    float* out = (float*)d_out;

    dim3 grid((NVEH + 5) / 6);   // 683 blocks, 6 vehicles each (3 packed pairs)
    dim3 block(64);
    hipLaunchKernelGGL(rnncf_kernel, grid, block, 0, stream,
                       x, st0, hs, K, R, bias, W2, b2, Wlc, blc, W1, b1, out);
}

// Round 7
// 690.312 us; speedup vs baseline: 1.4239x; 1.4239x over previous
//
#include <hip/hip_runtime.h>
#include <cstdint>

#define NVEH  4096
#define NT    1024
#define INW   12
#define UNITS 20

typedef float f32x2 __attribute__((ext_vector_type(2)));

#define PIN(v)  asm volatile("" : "+v"(v))

// Packed dual-FMA (VOP3P): acc.lo += w.lo * s, acc.hi += w.hi * s
// where s is the LOW half of the pair operand (op_sel_hi[src1]=0 broadcasts lo).
#define PKFMA_LO(acc, w, s2) \
    asm("v_pk_fma_f32 %0, %1, %2, %0 op_sel:[0,0,0] op_sel_hi:[1,0,1]" \
        : "+v"(acc) : "v"(w), "v"(s2))
// Same but broadcasting the HIGH half of the pair operand.
#define PKFMA_HI(acc, w, s2) \
    asm("v_pk_fma_f32 %0, %1, %2, %0 op_sel:[0,1,0] op_sel_hi:[1,1,1]" \
        : "+v"(acc) : "v"(w), "v"(s2))
// Packed mul, broadcasting low half of src1 (chain-head init, saves movs)
#define PKMUL_LO(dst, w, s2) \
    asm("v_pk_mul_f32 %0, %1, %2 op_sel:[0,0] op_sel_hi:[1,0]" \
        : "=v"(dst) : "v"(w), "v"(s2))
// Full element-wise packed fma: acc += a * b (both halves independent)
#define PKFMA(acc, a, b) \
    asm("v_pk_fma_f32 %0, %1, %2, %0" : "+v"(acc) : "v"(a), "v"(b))

__device__ __forceinline__ float fexp2(float x) { return __builtin_amdgcn_exp2f(x); }
__device__ __forceinline__ float frcp(float x)  { return __builtin_amdgcn_rcpf(x); }

// async global -> LDS, 16B per active lane, dest = uniform base + lane*16
__device__ __forceinline__ void gload_lds16(const float* g, float* l) {
    __builtin_amdgcn_global_load_lds(
        (const __attribute__((address_space(1))) unsigned int*)g,
        (__attribute__((address_space(3))) unsigned int*)l,
        16, 0, 0);
}

// r3 layout (3 veh/wave, 1366 waves) with the loop SOFTWARE-ROTATED:
// all h-independent work of step t+1 (x-read, K-dot) and the x2 read are
// hoisted into step t's latency shadow. The wave is in-order; the compiler
// does not rotate across the back-edge on its own (r5 evidence).
__global__ __attribute__((amdgpu_waves_per_eu(2, 2))) __launch_bounds__(64)
void rnncf_kernel(const float* __restrict__ x,          // (NVEH, NT, 12)
                  const float* __restrict__ init_state, // (NVEH, 2)
                  const float* __restrict__ hs,         // (2, NVEH, 20)
                  const float* __restrict__ K,          // (12, 80)
                  const float* __restrict__ R,          // (20, 80)
                  const float* __restrict__ bias,       // (80)
                  const float* __restrict__ W2,         // (20, 10)
                  const float* __restrict__ b2,         // (10)
                  const float* __restrict__ Wlc,        // (10, 3)
                  const float* __restrict__ blc,        // (3)
                  const float* __restrict__ W1,         // (10, 1)
                  const float* __restrict__ b1,         // (1)
                  float* __restrict__ out)
{
    const int lane = threadIdx.x;
    const int grp  = lane / 20;     // 0..2 = vehicle slot, 3 = idle lanes 60..63
    const int sub  = lane % 20;     // unit index / head index
    const int veh  = blockIdx.x * 3 + grp;
    const bool active = (grp < 3) && (veh < NVEH);
    const int vs = active ? veh : 0;

    __shared__ __align__(16) float x_lds[8][4][12];   // depth-8 x FIFO
    __shared__ __align__(16) float h_lds[4][20];
    __shared__ __align__(16) float x2_lds[4][12];

    // ---- folded weights: input-transform coefs AND gate exp2 scale baked in
    // (r4-verified math). zKx = bz + sum K''*x_raw is pos-free; the pos term
    // is a single kd*pos FMA at join time.
    const float L2E = 1.4426950408889634f;
    const float sI = -L2E, sF = -L2E, sG = 2.0f * L2E, sO = -L2E;
    f32x2 K01[12], K23[12], R01[20], R23[20], bz01, bz23, kd01, kd23;
#pragma unroll
    for (int k = 0; k < 12; ++k) {
        float ck = (k < 3) ? 0.01f : (k < 6) ? -0.01f : 0.025f;
        K01[k][0] = sI * ck * K[k * 80 + sub];
        K01[k][1] = sF * ck * K[k * 80 + 20 + sub];
        K23[k][0] = sG * ck * K[k * 80 + 40 + sub];
        K23[k][1] = sO * ck * K[k * 80 + 60 + sub];
    }
    {
        float aI = 0, aF = 0, aG = 0, aO = 0;
        for (int k = 0; k < 6; ++k) {
            float sgn = (k < 3) ? -0.01f : 0.01f;
            aI += sgn * K[k * 80 + sub];
            aF += sgn * K[k * 80 + 20 + sub];
            aG += sgn * K[k * 80 + 40 + sub];
            aO += sgn * K[k * 80 + 60 + sub];
        }
        kd01[0] = sI * aI; kd01[1] = sF * aF;
        kd23[0] = sG * aG; kd23[1] = sO * aO;
    }
    bz01[0] = sI * bias[sub];      bz01[1] = sF * bias[20 + sub];
    bz23[0] = sG * bias[40 + sub]; bz23[1] = sO * bias[60 + sub];
#pragma unroll
    for (int k = 0; k < 20; ++k) {
        R01[k][0] = sI * R[k * 80 + sub];      R01[k][1] = sF * R[k * 80 + 20 + sub];
        R23[k][0] = sG * R[k * 80 + 40 + sub]; R23[k][1] = sO * R[k * 80 + 60 + sub];
    }
    const int mh = (sub < 10) ? sub : 9;
    f32x2 W2p[10];
#pragma unroll
    for (int u = 0; u < 10; ++u) {
        W2p[u][0] = W2[(2 * u) * 10 + mh];
        W2p[u][1] = W2[(2 * u + 1) * 10 + mh];
    }
    float b2s = b2[mh];
    const int jl = (sub < 3) ? sub : 0;
    f32x2 Wlcp[5];
#pragma unroll
    for (int m = 0; m < 5; ++m) {
        Wlcp[m][0] = Wlc[(2 * m) * 3 + jl];
        Wlcp[m][1] = Wlc[(2 * m + 1) * 3 + jl];
    }
    float blcs = blc[jl];
    PIN(bz01); PIN(bz23); PIN(kd01); PIN(kd23);
#pragma unroll
    for (int k = 0; k < 12; ++k) { PIN(K01[k]); PIN(K23[k]); }
#pragma unroll
    for (int k = 0; k < 20; ++k) { PIN(R01[k]); PIN(R23[k]); }
#pragma unroll
    for (int u = 0; u < 10; ++u) PIN(W2p[u]);
#pragma unroll
    for (int m = 0; m < 5; ++m) PIN(Wlcp[m]);
    PIN(b2s); PIN(blcs);

    // ---- state ----
    float pos = init_state[vs * 2 + 0];
    float spd = init_state[vs * 2 + 1];
    float c   = hs[(size_t)NVEH * UNITS + (size_t)vs * UNITS + sub];
    float hnew = hs[(size_t)vs * UNITS + sub];

    // ---- deep x FIFO: lanes 0..8 stage 16B/step directly into LDS ----
    const bool stg = (lane < 9);
    int sveh = blockIdx.x * 3 + lane / 3;
    if (sveh > NVEH - 1) sveh = NVEH - 1;
    const float* sgp = x + (size_t)sveh * NT * INW + (lane % 3) * 4;
    if (stg) {
#pragma unroll
        for (int t0 = 0; t0 < 8; ++t0)
            gload_lds16(sgp + (size_t)t0 * INW, &x_lds[t0][0][0]);
    }

    // ---- initial h exchange ----
    h_lds[grp][sub] = hnew;
    __builtin_amdgcn_wave_barrier();
    f32x2 hrp[10];
#pragma unroll
    for (int q = 0; q < 5; ++q) {
        float4 v = ((const float4*)&h_lds[grp][0])[q];
        hrp[2*q][0]   = v.x; hrp[2*q][1]   = v.y;
        hrp[2*q+1][0] = v.z; hrp[2*q+1][1] = v.w;
    }
    __builtin_amdgcn_wave_barrier();

    // ---- prologue: zKx(0) from x(0), zA/zB(0) from h0 ----
    asm volatile("s_waitcnt vmcnt(7)" ::: "memory");   // slot 0 resident
    f32x2 zKx01, zKx23, zA01, zA23, zB01, zB23;
    {
        float4 u0 = ((const float4*)&x_lds[0][grp][0])[0];
        float4 u1 = ((const float4*)&x_lds[0][grp][0])[1];
        float4 u2 = ((const float4*)&x_lds[0][grp][0])[2];
        f32x2 xp[6];
        xp[0][0]=u0.x; xp[0][1]=u0.y; xp[1][0]=u0.z; xp[1][1]=u0.w;
        xp[2][0]=u1.x; xp[2][1]=u1.y; xp[3][0]=u1.z; xp[3][1]=u1.w;
        xp[4][0]=u2.x; xp[4][1]=u2.y; xp[5][0]=u2.z; xp[5][1]=u2.w;
        zKx01 = bz01; zKx23 = bz23;
#pragma unroll
        for (int q = 0; q < 6; ++q) {
            PKFMA_LO(zKx01, K01[2*q],   xp[q]);
            PKFMA_LO(zKx23, K23[2*q],   xp[q]);
            PKFMA_HI(zKx01, K01[2*q+1], xp[q]);
            PKFMA_HI(zKx23, K23[2*q+1], xp[q]);
        }
    }
    PKMUL_LO(zA01, R01[0], hrp[0]);
    PKMUL_LO(zA23, R23[0], hrp[0]);
    PKFMA_HI(zA01, R01[1], hrp[0]);
    PKFMA_HI(zA23, R23[1], hrp[0]);
#pragma unroll
    for (int q = 1; q < 5; ++q) {
        PKFMA_LO(zA01, R01[2*q],   hrp[q]);
        PKFMA_LO(zA23, R23[2*q],   hrp[q]);
        PKFMA_HI(zA01, R01[2*q+1], hrp[q]);
        PKFMA_HI(zA23, R23[2*q+1], hrp[q]);
    }
    PKMUL_LO(zB01, R01[10], hrp[5]);
    PKMUL_LO(zB23, R23[10], hrp[5]);
    PKFMA_HI(zB01, R01[11], hrp[5]);
    PKFMA_HI(zB23, R23[11], hrp[5]);
#pragma unroll
    for (int q = 6; q < 10; ++q) {
        PKFMA_LO(zB01, R01[2*q],   hrp[q]);
        PKFMA_LO(zB23, R23[2*q],   hrp[q]);
        PKFMA_HI(zB01, R01[2*q+1], hrp[q]);
        PKFMA_HI(zB23, R23[2*q+1], hrp[q]);
    }

    f32x2 x2p[5];          // x2(t-1), carried; step 0 guarded
#pragma unroll
    for (int q = 0; q < 5; ++q) { x2p[q][0] = 0.0f; x2p[q][1] = 0.0f; }
    f32x2 posp; posp[0] = pos; posp[1] = 0.0f;

    float* trajp = out + (size_t)vs * NT;
    float* lcp   = out + (size_t)NVEH * NT + (size_t)vs * NT * 3;

    for (int tb = 0; tb < NT; tb += 4) {
        // rotated body touches slots tb+1..tb+4 -> oldest outstanding (tb+4)
        // must be drained: vmcnt(3). Loads stay >=3 in flight, never 0.
        asm volatile("s_waitcnt vmcnt(3)" ::: "memory");

#pragma unroll
        for (int j = 0; j < 4; ++j) {
            const int t = tb + j;

            // ---- A: head finish acc(t-1)->spd_t; pos update ----
            if (t > 0) {
                float a0 = b1[0], a1 = 0.0f;
#pragma unroll
                for (int m = 0; m < 5; ++m) {
                    a0 = fmaf(x2p[m][0], W1[2*m],   a0);
                    a1 = fmaf(x2p[m][1], W1[2*m+1], a1);
                }
                float accr = a0 + a1;
                spd = fmaf(0.1f, fmaf(10.0f, accr, -6.0f), spd);
                if (active && sub < 3) {
                    f32x2 lc2; lc2[0] = blcs; lc2[1] = 0.0f;
#pragma unroll
                    for (int m = 0; m < 5; ++m) PKFMA(lc2, x2p[m], Wlcp[m]);
                    lcp[(t - 1) * 3 + sub] = lc2[0] + lc2[1];
                }
            }
            const float pold = pos;           // inp(t) uses pos_{t-1}
            pos = fmaf(0.1f, spd, pold);
            if (active && sub == 0) trajp[t] = pos;
            posp[0] = pold;

            // ---- B: z(t) join: zKx + kd*pos_old + zA + zB ----
            f32x2 z01 = zKx01, z23 = zKx23;
            PKFMA_LO(z01, kd01, posp);
            PKFMA_LO(z23, kd23, posp);
            z01 = (z01 + zA01) + zB01;
            z23 = (z23 + zA23) + zB23;

            // ---- C: cell update ----
            float ig = frcp(1.0f + fexp2(z01[0]));
            float fg = frcp(1.0f + fexp2(z01[1]));
            float gg = 1.0f - 2.0f * frcp(fexp2(z23[0]) + 1.0f);
            float og = frcp(1.0f + fexp2(z23[1]));
            c = fmaf(fg, c, ig * gg);
            float th = 1.0f - 2.0f * frcp(fexp2(2.8853900817779268f * c) + 1.0f);
            hnew = og * th;

            // ---- D: h exchange ----
            h_lds[grp][sub] = hnew;
#pragma unroll
            for (int q = 0; q < 5; ++q) {
                float4 v = ((const float4*)&h_lds[grp][0])[q];
                hrp[2*q][0]   = v.x; hrp[2*q][1]   = v.y;
                hrp[2*q+1][0] = v.z; hrp[2*q+1][1] = v.w;
            }

            // ---- E: head part 1 + x2 round trip (read hoisted to here) ----
            f32x2 xm2; xm2[0] = b2s; xm2[1] = 0.0f;
#pragma unroll
            for (int u = 0; u < 10; ++u) PKFMA(xm2, hrp[u], W2p[u]);
            float xm = fmaxf(xm2[0] + xm2[1], 0.0f);
            if (sub < 10) x2_lds[grp][sub] = xm;
            {
                float4 a = ((const float4*)&x2_lds[grp][0])[0];
                float4 b = ((const float4*)&x2_lds[grp][0])[1];
                float2 e = *((const float2*)&x2_lds[grp][8]);
                x2p[0][0]=a.x; x2p[0][1]=a.y; x2p[1][0]=a.z; x2p[1][1]=a.w;
                x2p[2][0]=b.x; x2p[2][1]=b.y; x2p[3][0]=b.z; x2p[3][1]=b.w;
                x2p[4][0]=e.x; x2p[4][1]=e.y;
            }

            // ---- F: R-dots for t+1 (independent of E, fills its stalls) ----
            PKMUL_LO(zA01, R01[0], hrp[0]);
            PKMUL_LO(zA23, R23[0], hrp[0]);
            PKFMA_HI(zA01, R01[1], hrp[0]);
            PKFMA_HI(zA23, R23[1], hrp[0]);
#pragma unroll
            for (int q = 1; q < 5; ++q) {
                PKFMA_LO(zA01, R01[2*q],   hrp[q]);
                PKFMA_LO(zA23, R23[2*q],   hrp[q]);
                PKFMA_HI(zA01, R01[2*q+1], hrp[q]);
                PKFMA_HI(zA23, R23[2*q+1], hrp[q]);
            }
            PKMUL_LO(zB01, R01[10], hrp[5]);
            PKMUL_LO(zB23, R23[10], hrp[5]);
            PKFMA_HI(zB01, R01[11], hrp[5]);
            PKFMA_HI(zB23, R23[11], hrp[5]);
#pragma unroll
            for (int q = 6; q < 10; ++q) {
                PKFMA_LO(zB01, R01[2*q],   hrp[q]);
                PKFMA_LO(zB23, R23[2*q],   hrp[q]);
                PKFMA_HI(zB01, R01[2*q+1], hrp[q]);
                PKFMA_HI(zB23, R23[2*q+1], hrp[q]);
            }

            // ---- G: x-read + K-dot for t+1 (fully independent) ----
            {
                int tn = t + 1; if (tn > NT - 1) tn = NT - 1;
                float4 u0 = ((const float4*)&x_lds[tn & 7][grp][0])[0];
                float4 u1 = ((const float4*)&x_lds[tn & 7][grp][0])[1];
                float4 u2 = ((const float4*)&x_lds[tn & 7][grp][0])[2];
                f32x2 xp[6];
                xp[0][0]=u0.x; xp[0][1]=u0.y; xp[1][0]=u0.z; xp[1][1]=u0.w;
                xp[2][0]=u1.x; xp[2][1]=u1.y; xp[3][0]=u1.z; xp[3][1]=u1.w;
                xp[4][0]=u2.x; xp[4][1]=u2.y; xp[5][0]=u2.z; xp[5][1]=u2.w;
                zKx01 = bz01; zKx23 = bz23;
#pragma unroll
                for (int q = 0; q < 6; ++q) {
                    PKFMA_LO(zKx01, K01[2*q],   xp[q]);
                    PKFMA_LO(zKx23, K23[2*q],   xp[q]);
                    PKFMA_HI(zKx01, K01[2*q+1], xp[q]);
                    PKFMA_HI(zKx23, K23[2*q+1], xp[q]);
                }
            }
        }

        // issue loads for steps tb+8 .. tb+11 into the slots just consumed
        if (stg) {
#pragma unroll
            for (int j = 0; j < 4; ++j) {
                int tt = tb + 8 + j; if (tt > NT - 1) tt = NT - 1;
                gload_lds16(sgp + (size_t)tt * INW, &x_lds[(tb + j) & 7][0][0]);
            }
        }
    }

    // ---- epilogue: finish head for step NT-1 (x2p = x2(NT-1)) ----
    {
        float a0 = b1[0], a1 = 0.0f;
#pragma unroll
        for (int m = 0; m < 5; ++m) {
            a0 = fmaf(x2p[m][0], W1[2*m],   a0);
            a1 = fmaf(x2p[m][1], W1[2*m+1], a1);
        }
        float accr = a0 + a1;
        spd = fmaf(0.1f, fmaf(10.0f, accr, -6.0f), spd);
        if (active && sub < 3) {
            f32x2 lc2; lc2[0] = blcs; lc2[1] = 0.0f;
#pragma unroll
            for (int m = 0; m < 5; ++m) PKFMA(lc2, x2p[m], Wlcp[m]);
            lcp[(NT - 1) * 3 + sub] = lc2[0] + lc2[1];
        }
    }

    if (active) {
        float* spdf = out + (size_t)NVEH * NT * 4;
        float* hf   = spdf + NVEH;
        float* cf   = hf + (size_t)NVEH * UNITS;
        if (sub == 0) spdf[veh] = spd;
        hf[(size_t)veh * UNITS + sub] = hnew;
        cf[(size_t)veh * UNITS + sub] = c;
    }
}

extern "C" void kernel_launch(void* const* d_in, const int* in_sizes, int n_in,
                              void* d_out, int out_size, void* d_ws, size_t ws_size,
                              hipStream_t stream) {
    const float* x    = (const float*)d_in[0];
    const float* st0  = (const float*)d_in[1];
    const float* hs   = (const float*)d_in[2];
    const float* K    = (const float*)d_in[3];
    const float* R    = (const float*)d_in[4];
    const float* bias = (const float*)d_in[5];
    const float* W2   = (const float*)d_in[6];
    const float* b2   = (const float*)d_in[7];
    const float* Wlc  = (const float*)d_in[8];
    const float* blc  = (const float*)d_in[9];
    const float* W1   = (const float*)d_in[10];
    const float* b1   = (const float*)d_in[11];
    float* out = (float*)d_out;

    dim3 grid((NVEH + 2) / 3);   // 1366 blocks, 3 vehicles each
    dim3 block(64);
    hipLaunchKernelGGL(rnncf_kernel, grid, block, 0, stream,
                       x, st0, hs, K, R, bias, W2, b2, Wlc, blc, W1, b1, out);
}